// Round 10
// baseline (8977.549 us; speedup 1.0000x reference)
//
#include <hip/hip_runtime.h>

// PositionCloser round 23: split the step's MFMAs across TWO cooperating
// waves. R15/R21/R22 all plateau at ~1030 cyc/step = 512 MFMA single-wave
// issue floor + ~520 chain; scheduling variants proved the issue train is
// the floor. Fix: wave0 = gates i,g + c/h state (16 MFMA, bperm A-frags);
// wave1 = gates f,o (16 MFMA, A-frags read straight from the published h
// row as broadcast ds_read_b128) + the LOSS fused in lockstep (row gs-2
// per step; its x-loads are the same global data). Handoffs: wave0 -> h row
// (hring[4], rtz f16) + hflag (relaxed store, asm barrier, DS in-order
// commit); wave1 -> fg/og as self-validating {bits, bits^gs} b64 (per-lane
// b64 LDS writes are atomic; XOR tag = exact freshness, no fences, comm
// arrays zeroed at init so stale tags can't false-hit). f-tiles first so
// fg lands right when wave0's c-update needs it; og under the tanh chain.
// prod/cons + 32KB ring machinery deleted (loss is lockstep; LDS ~2KB).
// Deadlock audit: w1(gs) <- w0(gs-1) <- w1(gs-1): acyclic.

#define CH  128
#define HID 64

typedef __fp16 half8 __attribute__((ext_vector_type(8)));
typedef float  f32x4 __attribute__((ext_vector_type(4)));
typedef int    int4v __attribute__((ext_vector_type(4)));

#define MFMA16(A, B, C) __builtin_amdgcn_mfma_f32_16x16x32_f16((A), (B), (C), 0, 0, 0)

__device__ __forceinline__ float rlf(float v, int l) {
  return __builtin_bit_cast(float, __builtin_amdgcn_readlane(__builtin_bit_cast(int, v), l));
}
__device__ __forceinline__ int packh(float a, float b) {
  return __builtin_bit_cast(int, __builtin_amdgcn_cvt_pkrtz(a, b));
}
__device__ __forceinline__ float frcp(float x) { return __builtin_amdgcn_rcpf(x); }
__device__ __forceinline__ float sigm(float x) { return frcp(1.0f + __expf(-x)); }
__device__ __forceinline__ float tanh_(float x) {
  float e = __expf(2.0f * x);
  return 1.0f - 2.0f * frcp(e + 1.0f);
}
template <int CTRL, int RMASK>
__device__ __forceinline__ float dpp_add(float v) {
  int x = __builtin_amdgcn_update_dpp(0, __builtin_bit_cast(int, v), CTRL, RMASK, 0xF, true);
  return v + __builtin_bit_cast(float, x);
}
__device__ __forceinline__ float dpp_xor1(float v) {  // quad_perm [1,0,3,2]
  int x = __builtin_amdgcn_update_dpp(0, __builtin_bit_cast(int, v), 0xB1, 0xF, 0xF, true);
  return __builtin_bit_cast(float, x);
}
__device__ __forceinline__ float dpp_wave_sum(float v) {  // total lands in lane 63
  v = dpp_add<0x111, 0xF>(v);
  v = dpp_add<0x112, 0xF>(v);
  v = dpp_add<0x114, 0xF>(v);
  v = dpp_add<0x118, 0xF>(v);
  v = dpp_add<0x142, 0xA>(v);   // row_bcast:15
  v = dpp_add<0x143, 0xC>(v);   // row_bcast:31
  return v;
}
__device__ __forceinline__ unsigned long long enc_tag(float v, int gs) {
  const unsigned b = __builtin_bit_cast(unsigned, v);
  return (unsigned long long)b | ((unsigned long long)(b ^ (unsigned)gs) << 32);
}

__global__ __attribute__((amdgpu_flat_work_group_size(128, 128), amdgpu_waves_per_eu(2, 2)))
void pc_lstm_kernel(const int* __restrict__ inds,
                    const float* __restrict__ p,
                    const float* __restrict__ ls_probs,
                    const float* __restrict__ open_probs,
                    const int* __restrict__ open_slices,
                    const float* __restrict__ open_hx,
                    const float* __restrict__ W_ih,
                    const float* __restrict__ W_hh,
                    const float* __restrict__ b_ih,
                    const float* __restrict__ b_hh,
                    const float* __restrict__ W_out,
                    const float* __restrict__ b_out,
                    const int* __restrict__ n_chunks_p,
                    float* __restrict__ out)
{
  __shared__ __fp16 hring[4][HID];              // 512 B: last 4 h rows (rtz f16)
  __shared__ unsigned long long commF[HID];     // {bits(fg), bits^gs}
  __shared__ unsigned long long commO[HID];     // {bits(og), bits^gs}
  __shared__ int hflag;                         // last published step

  const int tid  = threadIdx.x;
  const int wv   = tid >> 6;           // 0 = main (i,g,state), 1 = helper (f,o)+loss
  const int lane = tid & 63;
  const int s    = blockIdx.x;         // one sequence per block
  const int n_chunks = n_chunks_p[0];
  const int NSTEP = n_chunks * CH;
  const int tbase = inds[s >> 4] + (s & 15);
  const float2* p2 = (const float2*)p;
  const int kg = lane >> 4;
  const int cc = lane & 15;
  const bool u1 = (lane & 16) != 0;
  const bool u2 = (lane & 32) != 0;
  const f32x4 zero4 = {0.f, 0.f, 0.f, 0.f};

  if (tid < HID) { commF[tid] = 0ull; commO[tid] = 0ull; }
  if (tid == 0) hflag = -1;
  __syncthreads();                      // only barrier in the kernel

  if (wv == 0) {
    // ============ main wave: gates i,g; owns h,c; publishes h ============
    half8 Wb[16];
#pragma unroll
    for (int ti = 0; ti < 8; ++ti) {
      const int t = (ti < 4) ? ti : ti + 4;          // tiles 0..3 (i), 8..11 (g)
#pragma unroll
      for (int kc = 0; kc < 2; ++kc) {
        const float* wp = W_hh + (16 * t + cc) * HID + 32 * kc + 8 * kg;
        half8 w;
#pragma unroll
        for (int j = 0; j < 8; ++j) w[j] = (__fp16)wp[j];
        Wb[2 * ti + kc] = w;
      }
    }
    const float wxi0 = W_ih[2 * lane],                wxi1 = W_ih[2 * lane + 1];
    const float bbi  = b_ih[lane] + b_hh[lane];
    const float wxg0 = W_ih[2 * (2 * HID + lane)],    wxg1 = W_ih[2 * (2 * HID + lane) + 1];
    const float bbg  = b_ih[2 * HID + lane] + b_hh[2 * HID + lane];

    float h = open_hx[(s * 2 + 0) * HID + lane];
    float c = open_hx[(s * 2 + 1) * HID + lane];

    int ia0[4], ia1[4];
#pragma unroll
    for (int w = 0; w < 4; ++w) {
      ia0[w] = 4 * (8 * kg + 2 * w);
      ia1[w] = 4 * (32 + 8 * kg + 2 * w);
    }

    // seed h_0 (rtz image, same rounding the MFMA A-frags consume)
    int hp = packh(h, dpp_xor1(h));
    ((unsigned short*)&hring[0][0])[lane] = (unsigned short)(hp & 0xffff);
    asm volatile("" ::: "memory");
    __hip_atomic_store(&hflag, 0, __ATOMIC_RELAXED, __HIP_MEMORY_SCOPE_WORKGROUP);

    float2 curA = p2[tbase + lane];
    float2 curB = p2[tbase + HID + lane];
    float2 nxtA = curA, nxtB = curB;

    for (int off = 0; off < n_chunks; ++off) {
      if (off) { curA = nxtA; curB = nxtB; }
      const float px0 = rlf(curA.x, 0);
      const float px1 = rlf(curA.y, 0);
      float2 xA, xB;
      xA.x = curA.x - px0; xA.y = curA.y - px1;
      xB.x = curB.x - px0; xB.y = curB.y - px1;
      if (off + 1 < n_chunks) {
        const int nb = tbase + (off + 1) * CH;
        nxtA = p2[nb + lane];
        nxtB = p2[nb + HID + lane];
      }
#pragma unroll
      for (int hf = 0; hf < 2; ++hf) {
        const float xcx = hf ? xB.x : xA.x;
        const float xcy = hf ? xB.y : xA.y;
#pragma unroll 1
        for (int tl = 0; tl < 64; ++tl) {
          const int gs = off * CH + hf * 64 + tl + 1;
          int4v A0, A1;
#pragma unroll
          for (int w = 0; w < 4; ++w) A0[w] = __builtin_amdgcn_ds_bpermute(ia0[w], hp);
#pragma unroll
          for (int w = 0; w < 4; ++w) A1[w] = __builtin_amdgcn_ds_bpermute(ia1[w], hp);
          const half8 a0 = __builtin_bit_cast(half8, A0);   // k = 0..31
          const half8 a1 = __builtin_bit_cast(half8, A1);   // k = 32..63
          const float x0 = rlf(xcx, tl);
          const float x1 = rlf(xcy, tl);

          f32x4 q0 = MFMA16(a0, Wb[0],  zero4);
          f32x4 q1 = MFMA16(a0, Wb[2],  zero4);
          f32x4 q2 = MFMA16(a0, Wb[4],  zero4);
          f32x4 q3 = MFMA16(a0, Wb[6],  zero4);
          f32x4 s0 = MFMA16(a0, Wb[8],  zero4);
          f32x4 s1 = MFMA16(a0, Wb[10], zero4);
          f32x4 s2 = MFMA16(a0, Wb[12], zero4);
          f32x4 s3 = MFMA16(a0, Wb[14], zero4);
          q0 = MFMA16(a1, Wb[1],  q0);
          q1 = MFMA16(a1, Wb[3],  q1);
          q2 = MFMA16(a1, Wb[5],  q2);
          q3 = MFMA16(a1, Wb[7],  q3);
          s0 = MFMA16(a1, Wb[9],  s0);
          s1 = MFMA16(a1, Wb[11], s1);
          s2 = MFMA16(a1, Wb[13], s2);
          s3 = MFMA16(a1, Wb[15], s3);

          const float si01 = u1 ? q1[0] : q0[0];
          const float si23 = u1 ? q3[0] : q2[0];
          const float di   = u2 ? si23 : si01;
          const float pai  = fmaf(x0, wxi0, fmaf(x1, wxi1, di + bbi));
          const float ig   = sigm(pai);
          const float sg01 = u1 ? s1[0] : s0[0];
          const float sg23 = u1 ? s3[0] : s2[0];
          const float dg   = u2 ? sg23 : sg01;
          const float pag  = fmaf(x0, wxg0, fmaf(x1, wxg1, dg + bbg));
          const float gg   = tanh_(pag);

          float fg;
          for (;;) {
            const unsigned long long v =
                __hip_atomic_load(&commF[lane], __ATOMIC_RELAXED, __HIP_MEMORY_SCOPE_WORKGROUP);
            const unsigned lo = (unsigned)v, hi = (unsigned)(v >> 32);
            if ((lo ^ hi) == (unsigned)gs) { fg = __builtin_bit_cast(float, lo); break; }
          }
          c = fmaf(fg, c, ig * gg);
          const float tc = tanh_(c);

          float og;
          for (;;) {
            const unsigned long long v =
                __hip_atomic_load(&commO[lane], __ATOMIC_RELAXED, __HIP_MEMORY_SCOPE_WORKGROUP);
            const unsigned lo = (unsigned)v, hi = (unsigned)(v >> 32);
            if ((lo ^ hi) == (unsigned)gs) { og = __builtin_bit_cast(float, lo); break; }
          }
          h = og * tc;

          hp = packh(h, dpp_xor1(h));                 // next step's pairs + row image
          ((unsigned short*)&hring[gs & 3][0])[lane] = (unsigned short)(hp & 0xffff);
          asm volatile("" ::: "memory");
          __hip_atomic_store(&hflag, gs, __ATOMIC_RELAXED, __HIP_MEMORY_SCOPE_WORKGROUP);
        }
      }
    }
  } else {
    // ============ helper + loss wave: gates f,o; loss row gs-2 ============
    half8 Wb[16];
#pragma unroll
    for (int ti = 0; ti < 8; ++ti) {
      const int t = (ti < 4) ? (4 + ti) : (8 + ti);   // tiles 4..7 (f), 12..15 (o)
#pragma unroll
      for (int kc = 0; kc < 2; ++kc) {
        const float* wp = W_hh + (16 * t + cc) * HID + 32 * kc + 8 * kg;
        half8 w;
#pragma unroll
        for (int j = 0; j < 8; ++j) w[j] = (__fp16)wp[j];
        Wb[2 * ti + kc] = w;
      }
    }
    const float wxf0 = W_ih[2 * (1 * HID + lane)], wxf1 = W_ih[2 * (1 * HID + lane) + 1];
    const float bbf  = b_ih[1 * HID + lane] + b_hh[1 * HID + lane];
    const float wxo0 = W_ih[2 * (3 * HID + lane)], wxo1 = W_ih[2 * (3 * HID + lane) + 1];
    const float bbo  = b_ih[3 * HID + lane] + b_hh[3 * HID + lane];

    const float wo   = W_out[lane];
    const float bout = b_out[0];
    const int   os   = open_slices[s];
    const float OL   = __logf(p[2 * os]) + __logf(p[2 * os + 1]);
    const float coef = open_probs[s] * (2.0f * ls_probs[s] - 1.0f);

    float S = 1.0f, D = 1.0f, lsum = 0.0f, psum = 0.0f;
    float LAc = 0.f, LBc = 0.f, LAp = 0.f, LBp = 0.f;

    float2 curA = p2[tbase + lane];
    float2 curB = p2[tbase + HID + lane];
    float2 nxtA = curA, nxtB = curB;

    for (int off = 0; off < n_chunks; ++off) {
      if (off) { curA = nxtA; curB = nxtB; LAp = LAc; LBp = LBc; }
      LAc = __logf(curA.x) + __logf(curA.y);
      LBc = __logf(curB.x) + __logf(curB.y);
      const float px0 = rlf(curA.x, 0);
      const float px1 = rlf(curA.y, 0);
      float2 xA, xB;
      xA.x = curA.x - px0; xA.y = curA.y - px1;
      xB.x = curB.x - px0; xB.y = curB.y - px1;
      if (off + 1 < n_chunks) {
        const int nb = tbase + (off + 1) * CH;
        nxtA = p2[nb + lane];
        nxtB = p2[nb + HID + lane];
      }
#pragma unroll
      for (int hf = 0; hf < 2; ++hf) {
        const float xcx = hf ? xB.x : xA.x;
        const float xcy = hf ? xB.y : xA.y;
#pragma unroll 1
        for (int tl = 0; tl < 64; ++tl) {
          const int gs = off * CH + hf * 64 + tl + 1;
          while (__hip_atomic_load(&hflag, __ATOMIC_RELAXED, __HIP_MEMORY_SCOPE_WORKGROUP) < gs - 1) {}
          asm volatile("" ::: "memory");
          const __fp16* prow = &hring[(gs - 1) & 3][0];
          const half8 a0 = *(const half8*)((const char*)prow + 16 * kg);        // h[8kg..+7]
          const half8 a1 = *(const half8*)((const char*)prow + 64 + 16 * kg);   // h[32+8kg..]
          const float hv = (float)prow[lane];                                   // loss row h
          const float x0 = rlf(xcx, tl);
          const float x1 = rlf(xcy, tl);

          // f-gate first (wave0 needs fg before og)
          f32x4 q0 = MFMA16(a0, Wb[0],  zero4);
          f32x4 q1 = MFMA16(a0, Wb[2],  zero4);
          f32x4 q2 = MFMA16(a0, Wb[4],  zero4);
          f32x4 q3 = MFMA16(a0, Wb[6],  zero4);
          q0 = MFMA16(a1, Wb[1],  q0);
          q1 = MFMA16(a1, Wb[3],  q1);
          q2 = MFMA16(a1, Wb[5],  q2);
          q3 = MFMA16(a1, Wb[7],  q3);
          f32x4 r0 = MFMA16(a0, Wb[8],  zero4);
          f32x4 r1 = MFMA16(a0, Wb[10], zero4);
          const float sf01 = u1 ? q1[0] : q0[0];
          const float sf23 = u1 ? q3[0] : q2[0];
          const float df   = u2 ? sf23 : sf01;
          const float paf  = fmaf(x0, wxf0, fmaf(x1, wxf1, df + bbf));
          const float fgv  = sigm(paf);
          __hip_atomic_store(&commF[lane], enc_tag(fgv, gs),
                             __ATOMIC_RELAXED, __HIP_MEMORY_SCOPE_WORKGROUP);
          f32x4 r2 = MFMA16(a0, Wb[12], zero4);
          f32x4 r3 = MFMA16(a0, Wb[14], zero4);
          r0 = MFMA16(a1, Wb[9],  r0);
          r1 = MFMA16(a1, Wb[11], r1);
          r2 = MFMA16(a1, Wb[13], r2);
          r3 = MFMA16(a1, Wb[15], r3);
          const float so01 = u1 ? r1[0] : r0[0];
          const float so23 = u1 ? r3[0] : r2[0];
          const float dox  = u2 ? so23 : so01;
          const float pao  = fmaf(x0, wxo0, fmaf(x1, wxo1, dox + bbo));
          const float ogv  = sigm(pao);
          __hip_atomic_store(&commO[lane], enc_tag(ogv, gs),
                             __ATOMIC_RELAXED, __HIP_MEMORY_SCOPE_WORKGROUP);

          // fused loss for global row gs-2 (value h_{gs-1} = hv); skip at gs==1
          if (gs >= 2) {
            const int rp   = hf * 64 + tl - 1;        // -1 -> prev chunk, pos 127
            const float z  = rlf(dpp_wave_sum(hv * wo), 63);
            const float pr = sigm(z + bout);
            const int pos  = (rp < 0) ? (CH - 1) : rp;
            const float LA_ = (rp < 0) ? LAp : LAc;
            const float LB_ = (rp < 0) ? LBp : LBc;
            const float Lt = (pos < 64) ? rlf(LA_, pos) : rlf(LB_, pos - 64);
            const float pn = (pos == 0) ? pr : pr * D;
            lsum = fmaf(pn, Lt, lsum);
            psum += pn;
            if (pos == 0)           D = S * (1.0f - pr);   // chunk t=0 undiscounted (ref quirk)
            else if (pos < CH - 1)  D *= (1.0f - pr);
            else                    S = D;                  // carry excludes (1-p_last)
          }
        }
      }
    }
    // final loss row: h_NSTEP at pos 127 of the last chunk
    while (__hip_atomic_load(&hflag, __ATOMIC_RELAXED, __HIP_MEMORY_SCOPE_WORKGROUP) < NSTEP) {}
    asm volatile("" ::: "memory");
    const float hvN = (float)hring[NSTEP & 3][lane];
    const float zN  = rlf(dpp_wave_sum(hvN * wo), 63);
    const float prN = sigm(zN + bout);
    const float LtN = rlf(LBc, 63);
    const float pnN = prN * D;
    lsum = fmaf(pnN, LtN, lsum);
    psum += pnN;
    if (lane == 0) atomicAdd(out, coef * (lsum - OL * psum));
  }
}

extern "C" void kernel_launch(void* const* d_in, const int* in_sizes, int n_in,
                              void* d_out, int out_size, void* d_ws, size_t ws_size,
                              hipStream_t stream) {
  (void)hipMemsetAsync(d_out, 0, sizeof(float), stream);

  pc_lstm_kernel<<<dim3(1024), dim3(128), 0, stream>>>(
      (const int*)d_in[0],    // inds
      (const float*)d_in[1],  // p
      (const float*)d_in[2],  // ls_probs
      (const float*)d_in[3],  // open_probs
      (const int*)d_in[4],    // open_slices
      (const float*)d_in[5],  // open_hx
      (const float*)d_in[6],  // W_ih
      (const float*)d_in[7],  // W_hh
      (const float*)d_in[8],  // b_ih
      (const float*)d_in[9],  // b_hh
      (const float*)d_in[10], // W_out
      (const float*)d_in[11], // b_out
      (const int*)d_in[12],   // n_chunks
      (float*)d_out);
}